// Round 8
// baseline (202.876 us; speedup 1.0000x reference)
//
#include <hip/hip_runtime.h>
#include <hip/hip_bf16.h>

#define BSZ   2
#define LSEQ  4096
#define DH    512
#define NH    8
#define HDIM  64

typedef unsigned short ushort_t;
typedef __attribute__((ext_vector_type(8))) short s8v;    // 8 bf16 = 4 VGPRs
typedef __attribute__((ext_vector_type(4))) short s4v;    // 4 bf16 = 2 VGPRs
typedef __attribute__((ext_vector_type(4))) float f4v;    // MFMA accumulator

#define C_EXP 0.18033688011112042f   // 0.125 * log2(e)

__device__ __forceinline__ ushort_t f2bf(float f) {
    __hip_bfloat16 h = __float2bfloat16(f);
    return *(ushort_t*)&h;
}

__device__ __forceinline__ unsigned int fbits(float f) {
    union { float f; unsigned int u; } c; c.f = f; return c.u;
}

// pack two fp32 into bf16x2 by TRUNCATION (1-2 VALU ops vs ~5/elem RNE).
// Used only for P (softmax numerator): O and l use the same truncated
// values, so the bias cancels in O/l.
__device__ __forceinline__ unsigned int pk_trunc(float lo, float hi) {
    return (fbits(lo) >> 16) | (fbits(hi) & 0xFFFF0000u);
}

// async global->LDS, 16B per lane; LDS dest = wave-uniform base + lane*16B
__device__ __forceinline__ void gld_lds16(const ushort_t* g, ushort_t* l) {
    __builtin_amdgcn_global_load_lds(
        (const __attribute__((address_space(1))) void*)g,
        (__attribute__((address_space(3))) void*)l, 16, 0, 0);
}

// ---------------------------------------------------------------------------
// Fused prep: cast x->bf16, transpose both weights, zero O/l accumulators.
// (exact round-0 version)
// ---------------------------------------------------------------------------
__device__ __forceinline__ void transpose_tile(const float* __restrict__ src,
                                               ushort_t* __restrict__ dst,
                                               int R, int C, int bx, int by)
{
    __shared__ float tile[32][33];
    int r0 = by * 32, c0 = bx * 32;
    int t = threadIdx.x;
    int tr = t >> 5, tc = t & 31;
    #pragma unroll
    for (int i = 0; i < 4; i++)
        tile[tr + 8 * i][tc] = src[(size_t)(r0 + tr + 8 * i) * C + c0 + tc];
    __syncthreads();
    #pragma unroll
    for (int i = 0; i < 4; i++) {
        int oc = tr + 8 * i;
        dst[(size_t)(c0 + oc) * R + r0 + tc] = f2bf(tile[tc][oc]);
    }
}

__global__ __launch_bounds__(256) void prep(const float* __restrict__ x,
                                            ushort_t* __restrict__ xb,
                                            const float* __restrict__ w_in,
                                            ushort_t* __restrict__ w_inT,
                                            const float* __restrict__ w_out,
                                            ushort_t* __restrict__ w_outT,
                                            float* __restrict__ Oacc,
                                            float* __restrict__ lacc)
{
    int bx = blockIdx.x;
    if (bx < 4096) {
        int i = (bx * 256 + threadIdx.x) * 4;
        float4 v = *(const float4*)&x[i];
        ushort_t o[4] = {f2bf(v.x), f2bf(v.y), f2bf(v.z), f2bf(v.w)};
        *(uint2*)&xb[i] = *(uint2*)o;
    } else if (bx < 4864) {
        int idx = bx - 4096;                     // w_in: [512][1536] -> [1536][512]
        transpose_tile(w_in, w_inT, DH, 3 * DH, idx % 48, idx / 48);
    } else if (bx < 5120) {
        int idx = bx - 4864;                     // w_out: [512][512]
        transpose_tile(w_out, w_outT, DH, DH, idx % 16, idx / 16);
    } else if (bx < 9216) {
        int i = ((bx - 5120) * 256 + threadIdx.x) * 4;   // zero Oacc
        float4 z = {0.f, 0.f, 0.f, 0.f};
        *(float4*)&Oacc[i] = z;
    } else {
        int i = ((bx - 9216) * 256 + threadIdx.x) * 4;   // zero lacc
        float4 z = {0.f, 0.f, 0.f, 0.f};
        *(float4*)&lacc[i] = z;
    }
}

// ---------------------------------------------------------------------------
// bf16 MFMA GEMM (m97 structure, BK=32 -- exact round-0 config). QSCALE:
// multiply cols<512 by C_EXP (folds softmax scale into Q). VTRANS: cols>=1024
// (V) are written ONLY transposed into vtout[b*NH+h][d][l] (8B packed stores).
// ---------------------------------------------------------------------------
template <typename OUT, bool QSCALE, bool VTRANS>
__global__ __launch_bounds__(256) void gemm_bt(const ushort_t* __restrict__ A,
                                               const ushort_t* __restrict__ Bt,
                                               const float* __restrict__ bias,
                                               OUT* __restrict__ C,
                                               ushort_t* __restrict__ vtout,
                                               int M, int N, int K)
{
    __shared__ ushort_t As[128 * 32];
    __shared__ ushort_t Bs[128 * 32];
    const int tid = threadIdx.x;
    const int row0 = blockIdx.y * 128, col0 = blockIdx.x * 128;
    const int wid = tid >> 6, lane = tid & 63;
    const int wm = wid >> 1, wn = wid & 1;
    const int quad = lane >> 4, ln = lane & 15;

    f4v acc[4][4] = {};

    const int srow = (lane >> 2);
    const int scol = (lane & 3) * 8;

    for (int k0 = 0; k0 < K; k0 += 32) {
        #pragma unroll
        for (int t = 0; t < 2; t++) {
            int chunk = wid * 2 + t;
            int r = chunk * 16 + srow;
            gld_lds16(&A[(size_t)(row0 + r) * K + k0 + scol], &As[chunk * 512]);
            gld_lds16(&Bt[(size_t)(col0 + r) * K + k0 + scol], &Bs[chunk * 512]);
        }
        __syncthreads();
        s8v af[4], bf[4];
        #pragma unroll
        for (int mt = 0; mt < 4; mt++)
            af[mt] = *(const s8v*)&As[(wm * 64 + mt * 16 + ln) * 32 + quad * 8];
        #pragma unroll
        for (int nt = 0; nt < 4; nt++)
            bf[nt] = *(const s8v*)&Bs[(wn * 64 + nt * 16 + ln) * 32 + quad * 8];
        #pragma unroll
        for (int mt = 0; mt < 4; mt++)
            #pragma unroll
            for (int nt = 0; nt < 4; nt++)
                acc[mt][nt] = __builtin_amdgcn_mfma_f32_16x16x32_bf16(
                    af[mt], bf[nt], acc[mt][nt], 0, 0, 0);
        __syncthreads();
    }

    #pragma unroll
    for (int mt = 0; mt < 4; mt++) {
        #pragma unroll
        for (int nt = 0; nt < 4; nt++) {
            int c = col0 + wn * 64 + nt * 16 + ln;
            float bv = bias[c];
            float scl = 1.0f;
            if constexpr (QSCALE) scl = (c < DH) ? C_EXP : 1.0f;
            bool vcol = false;
            if constexpr (VTRANS) vcol = (c >= 2 * DH);
            if (vcol) {
                // transposed V store: vt[(b*NH+h)*64 + d][l], 4 contiguous l
                int d = c - 2 * DH;
                int hh = d >> 6, dd = d & 63;
                int r0 = row0 + wm * 64 + mt * 16 + quad * 4;
                int bb = r0 >> 12, l = r0 & (LSEQ - 1);
                ushort_t tmp[4];
                #pragma unroll
                for (int reg = 0; reg < 4; reg++)
                    tmp[reg] = f2bf(acc[mt][nt][reg] + bv);
                *(uint2*)&vtout[((size_t)((bb * NH + hh) * 64 + dd)) * LSEQ + l]
                    = *(uint2*)tmp;
            } else {
                #pragma unroll
                for (int reg = 0; reg < 4; reg++) {
                    int r = row0 + wm * 64 + mt * 16 + quad * 4 + reg;
                    float v = (acc[mt][nt][reg] + bv) * scl;
                    if constexpr (sizeof(OUT) == 2)
                        C[(size_t)r * N + c] = (OUT)f2bf(v);
                    else
                        C[(size_t)r * N + c] = v;
                }
            }
        }
    }
}

// ---------------------------------------------------------------------------
// Flash v14: PARITY K-split with shared K/V streaming. v9 processed its two
// q-tiles {63-p, p} sequentially, re-fetching K/V for the second even though
// its kt range is a subset of the first's. v14: block (p, parity) iterates
// kt in {parity, parity+2, ...} < n1 ONCE, and each staged K/V tile feeds
// BOTH q-tiles (tile b active while kt < n2). Per-(h,b) iterations drop
// 2080 -> 1552 (-25% staging bytes / barriers / LDS frag-reads); MFMA+exp2
// work conserved; still exactly 2 atomic writers per O/l address. Same
// per-iteration inner structure as v9 (frozen after rounds 2-4/6 lessons).
// Cost: both tiles' o_acc/qa live simultaneously (VGPR ~112 -> ~190; still
// 2 waves/SIMD). p is h,b-scrambled so same-CU blocks get mixed workloads.
// ---------------------------------------------------------------------------
__global__ __launch_bounds__(128) void flash_mfma(const ushort_t* __restrict__ qkv,
                                                  const ushort_t* __restrict__ vt,
                                                  float* __restrict__ Oacc,
                                                  float* __restrict__ lacc)
{
    __shared__ ushort_t Ks[64 * 72];   // [kseq][d]
    __shared__ ushort_t Vs[64 * 72];   // [d][kseq]

    const int x = blockIdx.x;          // 0..63
    const int h = blockIdx.y, b = blockIdx.z;
    const int parity = x & 1;
    const int p = ((x >> 1) + h * 4 + (b << 4)) & 31;   // bijective per (h,b)
    const int qtA = 63 - p, qtB = p;
    const int nA = qtA + 1, nB = qtB + 1;

    const int tid = threadIdx.x;
    const int w = tid >> 6, lane = tid & 63;   // w in {0,1}
    const int quad = lane >> 4, ln = lane & 15;

    const int sr = tid >> 1, sc = (tid & 1) * 32;   // staging: 2 threads/row
    const int ldsw = sr * 72 + sc;
    const size_t kstep = (size_t)64 * 3 * DH;

    const int qrow0A = qtA * 64 + w * 32;
    const int qrow0B = qtB * 64 + w * 32;

    // Q B-frags for BOTH tiles (pre-scaled by C_EXP), loop-invariant
    s8v qa[2][2][2];   // [tile][qg][half]
    #pragma unroll
    for (int t = 0; t < 2; t++) {
        const int qr0 = t ? qrow0B : qrow0A;
        #pragma unroll
        for (int qg = 0; qg < 2; qg++) {
            const ushort_t* qrow = qkv
                + ((size_t)(b * LSEQ + qr0 + qg * 16 + ln)) * (3 * DH) + h * HDIM;
            qa[t][qg][0] = *(const s8v*)(qrow + quad * 8);
            qa[t][qg][1] = *(const s8v*)(qrow + 32 + quad * 8);
        }
    }

    float l_s[2][2] = {};
    f4v o_acc[2][2][4] = {};

    size_t gk = ((size_t)(b * LSEQ + parity * 64 + sr)) * (3 * DH) + DH + h * HDIM + sc;
    size_t gv = ((size_t)((b * NH + h) * 64 + sr)) * LSEQ + parity * 64 + sc;
    uint4 pk0 = *(const uint4*)&qkv[gk];
    uint4 pk1 = *(const uint4*)&qkv[gk + 8];
    uint4 pk2 = *(const uint4*)&qkv[gk + 16];
    uint4 pk3 = *(const uint4*)&qkv[gk + 24];
    uint4 pv0 = *(const uint4*)&vt[gv];
    uint4 pv1 = *(const uint4*)&vt[gv + 8];
    uint4 pv2 = *(const uint4*)&vt[gv + 16];
    uint4 pv3 = *(const uint4*)&vt[gv + 24];

    for (int kt = parity; kt < nA; kt += 2) {
        const int k0 = kt * 64;
        __syncthreads();   // all waves done reading prev Ks/Vs
        *(uint4*)&Ks[ldsw]      = pk0;
        *(uint4*)&Ks[ldsw + 8]  = pk1;
        *(uint4*)&Ks[ldsw + 16] = pk2;
        *(uint4*)&Ks[ldsw + 24] = pk3;
        *(uint4*)&Vs[ldsw]      = pv0;
        *(uint4*)&Vs[ldsw + 8]  = pv1;
        *(uint4*)&Vs[ldsw + 16] = pv2;
        *(uint4*)&Vs[ldsw + 24] = pv3;
        if (kt + 2 < nA) {
            gk += 2 * kstep; gv += 128;
            pk0 = *(const uint4*)&qkv[gk];
            pk1 = *(const uint4*)&qkv[gk + 8];
            pk2 = *(const uint4*)&qkv[gk + 16];
            pk3 = *(const uint4*)&qkv[gk + 24];
            pv0 = *(const uint4*)&vt[gv];
            pv1 = *(const uint4*)&vt[gv + 8];
            pv2 = *(const uint4*)&vt[gv + 16];
            pv3 = *(const uint4*)&vt[gv + 24];
        }
        __syncthreads();

        // K frags (b128) + V frags (b64 per 16-k chunk), read ONCE, used by
        // both q-tiles
        s8v kb[4][2];
        #pragma unroll
        for (int nt = 0; nt < 4; nt++) {
            kb[nt][0] = *(const s8v*)&Ks[(nt * 16 + ln) * 72 + quad * 8];
            kb[nt][1] = *(const s8v*)&Ks[(nt * 16 + ln) * 72 + 32 + quad * 8];
        }
        s4v vf[4][4];   // [dt][chunk]
        #pragma unroll
        for (int dt = 0; dt < 4; dt++)
            #pragma unroll
            for (int nt = 0; nt < 4; nt++)
                vf[dt][nt] = *(const s4v*)&Vs[(dt * 16 + ln) * 72 + nt * 16 + quad * 4];

        auto do_tile = [&](int qt_, int qrow0_, s8v (&qa_)[2][2],
                           float (&ls_)[2], f4v (&oa_)[2][4]) {
            #pragma unroll
            for (int qg = 0; qg < 2; qg++) {
                // S^T[k0+nt*16+quad*4+reg][qrow0_+qg*16+ln]
                f4v s[4] = {};
                #pragma unroll
                for (int nt = 0; nt < 4; nt++) {
                    s[nt] = __builtin_amdgcn_mfma_f32_16x16x32_bf16(kb[nt][0], qa_[qg][0], s[nt], 0, 0, 0);
                    s[nt] = __builtin_amdgcn_mfma_f32_16x16x32_bf16(kb[nt][1], qa_[qg][1], s[nt], 0, 0, 0);
                }

                float pp[4][4];
                const int q = qrow0_ + qg * 16 + ln;
                if (kt == qt_) {
                    #pragma unroll
                    for (int nt = 0; nt < 4; nt++) {
                        #pragma unroll
                        for (int reg = 0; reg < 4; reg++) {
                            int kidx = k0 + nt * 16 + quad * 4 + reg;
                            bool valid = (kidx <= q) && (kidx >= 1 || q == 0);
                            pp[nt][reg] = valid ? __builtin_amdgcn_exp2f(s[nt][reg]) : 0.0f;
                        }
                    }
                } else {
                    #pragma unroll
                    for (int nt = 0; nt < 4; nt++)
                        #pragma unroll
                        for (int reg = 0; reg < 4; reg++)
                            pp[nt][reg] = __builtin_amdgcn_exp2f(s[nt][reg]);
                    if (kt == 0 && quad == 0)   // k==0 invalid (q >= 64 here)
                        pp[0][0] = 0.0f;
                }

                #pragma unroll
                for (int nt = 0; nt < 4; nt++)
                    ls_[qg] += (pp[nt][0] + pp[nt][1]) + (pp[nt][2] + pp[nt][3]);

                // P stays in registers: truncation-packed bf16 A-operand
                #pragma unroll
                for (int nt = 0; nt < 4; nt++) {
                    union { unsigned int u[2]; s4v v; } pk;
                    pk.u[0] = pk_trunc(pp[nt][0], pp[nt][1]);
                    pk.u[1] = pk_trunc(pp[nt][2], pp[nt][3]);
                    #pragma unroll
                    for (int dt = 0; dt < 4; dt++)
                        oa_[qg][dt] = __builtin_amdgcn_mfma_f32_16x16x16bf16_1k(
                            pk.v, vf[dt][nt], oa_[qg][dt], 0, 0, 0);
                }
            }
        };

        do_tile(qtA, qrow0A, qa[0], l_s[0], o_acc[0]);
        if (kt < nB)
            do_tile(qtB, qrow0B, qa[1], l_s[1], o_acc[1]);
    }

    // merge partials (device-scope atomics; 2 writers per address)
    #pragma unroll
    for (int t = 0; t < 2; t++) {
        const int qr0 = t ? qrow0B : qrow0A;
        #pragma unroll
        for (int qg = 0; qg < 2; qg++) {
            float lf = l_s[t][qg];
            lf += __shfl_xor(lf, 16);
            lf += __shfl_xor(lf, 32);
            if (quad == 0)
                atomicAdd(&lacc[((size_t)(b * NH + h)) * LSEQ + qr0 + qg * 16 + ln], lf);
            #pragma unroll
            for (int dt = 0; dt < 4; dt++)
                #pragma unroll
                for (int reg = 0; reg < 4; reg++)
                    atomicAdd(&Oacc[((size_t)(b * LSEQ + qr0 + qg * 16 + quad * 4 + reg)) * DH
                                    + h * HDIM + dt * 16 + ln],
                              o_acc[t][qg][dt][reg]);
        }
    }
}

// ---------------------------------------------------------------------------
// att[b,l,h*64+d] = Oacc / lacc  (fp32 -> bf16). 16 elems/thread.
// (exact round-0 version -- the gemm-fused variant measured +5us, reverted)
// ---------------------------------------------------------------------------
__global__ __launch_bounds__(256) void normalize(const float* __restrict__ Oacc,
                                                 const float* __restrict__ lacc,
                                                 ushort_t* __restrict__ att)
{
    int t = blockIdx.x * 256 + threadIdx.x;   // 262144 threads
    int row = t >> 5;                          // 0..8191
    int col0 = (t & 31) * 16;
    int h = col0 >> 6;
    int b = row >> 12, l = row & (LSEQ - 1);
    float linv = 1.0f / lacc[((size_t)(b * NH + h)) * LSEQ + l];
    const float* o = &Oacc[(size_t)row * DH + col0];
    ushort_t tmp[16];
    #pragma unroll
    for (int j = 0; j < 16; j++) tmp[j] = f2bf(o[j] * linv);
    size_t g = (size_t)row * DH + col0;
    *(uint4*)&att[g]     = *(uint4*)&tmp[0];
    *(uint4*)&att[g + 8] = *(uint4*)&tmp[8];
}

// ---------------------------------------------------------------------------
extern "C" void kernel_launch(void* const* d_in, const int* in_sizes, int n_in,
                              void* d_out, int out_size, void* d_ws, size_t ws_size,
                              hipStream_t stream)
{
    const float* x     = (const float*)d_in[0];  // [2,4096,512]
    const float* w_in  = (const float*)d_in[1];  // [512,1536]
    const float* b_in  = (const float*)d_in[2];  // [1536]
    const float* w_out = (const float*)d_in[3];  // [512,512]
    const float* b_out = (const float*)d_in[4];  // [512]
    float* out = (float*)d_out;                  // [2,4096,512] fp32

    const int M = BSZ * LSEQ;                    // 8192
    char* ws = (char*)d_ws;
    ushort_t* xb    = (ushort_t*)ws;                       ws += (size_t)M * DH * 2;        // 8.4MB
    ushort_t* w_inT = (ushort_t*)ws;                       ws += (size_t)3 * DH * DH * 2;   // 1.6MB
    ushort_t* w_outT= (ushort_t*)ws;                       ws += (size_t)DH * DH * 2;       // 0.5MB
    ushort_t* qkvb  = (ushort_t*)ws;                       ws += (size_t)M * 3 * DH * 2;    // 25.2MB
    ushort_t* vtb   = (ushort_t*)ws;                       ws += (size_t)M * DH * 2;        // 8.4MB
    ushort_t* attb  = (ushort_t*)ws;                       ws += (size_t)M * DH * 2;        // 8.4MB
    float*    Oacc  = (float*)ws;                          ws += (size_t)M * DH * 4;        // 16.8MB
    float*    lacc  = (float*)ws;                          /* 256KB */

    prep<<<9280, 256, 0, stream>>>(x, xb, w_in, w_inT, w_out, w_outT, Oacc, lacc);

    // qkv GEMM: scales Q cols by C_EXP, writes V cols transposed into vtb
    gemm_bt<ushort_t, true, true><<<dim3(3 * DH / 128, M / 128), 256, 0, stream>>>(
        xb, w_inT, b_in, qkvb, vtb, M, 3 * DH, DH);

    flash_mfma<<<dim3(64, NH, BSZ), 128, 0, stream>>>(qkvb, vtb, Oacc, lacc);

    normalize<<<1024, 256, 0, stream>>>(Oacc, lacc, attb);

    gemm_bt<float, false, false><<<dim3(DH / 128, M / 128), 256, 0, stream>>>(
        attb, w_outT, b_out, out, nullptr, M, DH, DH);
}

// Round 9
// 188.786 us; speedup vs baseline: 1.0746x; 1.0746x over previous
//
#include <hip/hip_runtime.h>
#include <hip/hip_bf16.h>

#define BSZ   2
#define LSEQ  4096
#define DH    512
#define NH    8
#define HDIM  64

typedef unsigned short ushort_t;
typedef __attribute__((ext_vector_type(8))) short s8v;    // 8 bf16 = 4 VGPRs
typedef __attribute__((ext_vector_type(4))) short s4v;    // 4 bf16 = 2 VGPRs
typedef __attribute__((ext_vector_type(4))) float f4v;    // MFMA accumulator

#define C_EXP 0.18033688011112042f   // 0.125 * log2(e)

__device__ __forceinline__ ushort_t f2bf(float f) {
    __hip_bfloat16 h = __float2bfloat16(f);
    return *(ushort_t*)&h;
}

__device__ __forceinline__ unsigned int fbits(float f) {
    union { float f; unsigned int u; } c; c.f = f; return c.u;
}

// pack two fp32 into bf16x2 by TRUNCATION (1-2 VALU ops vs ~5/elem RNE).
// Used only for P (softmax numerator): O and l use the same truncated
// values, so the bias cancels in O/l.
__device__ __forceinline__ unsigned int pk_trunc(float lo, float hi) {
    return (fbits(lo) >> 16) | (fbits(hi) & 0xFFFF0000u);
}

// async global->LDS, 16B per lane; LDS dest = wave-uniform base + lane*16B
__device__ __forceinline__ void gld_lds16(const ushort_t* g, ushort_t* l) {
    __builtin_amdgcn_global_load_lds(
        (const __attribute__((address_space(1))) void*)g,
        (__attribute__((address_space(3))) void*)l, 16, 0, 0);
}

// ---------------------------------------------------------------------------
// Fused prep: cast x->bf16, transpose both weights, zero O/l accumulators.
// (exact round-0 version)
// ---------------------------------------------------------------------------
__device__ __forceinline__ void transpose_tile(const float* __restrict__ src,
                                               ushort_t* __restrict__ dst,
                                               int R, int C, int bx, int by)
{
    __shared__ float tile[32][33];
    int r0 = by * 32, c0 = bx * 32;
    int t = threadIdx.x;
    int tr = t >> 5, tc = t & 31;
    #pragma unroll
    for (int i = 0; i < 4; i++)
        tile[tr + 8 * i][tc] = src[(size_t)(r0 + tr + 8 * i) * C + c0 + tc];
    __syncthreads();
    #pragma unroll
    for (int i = 0; i < 4; i++) {
        int oc = tr + 8 * i;
        dst[(size_t)(c0 + oc) * R + r0 + tc] = f2bf(tile[tc][oc]);
    }
}

__global__ __launch_bounds__(256) void prep(const float* __restrict__ x,
                                            ushort_t* __restrict__ xb,
                                            const float* __restrict__ w_in,
                                            ushort_t* __restrict__ w_inT,
                                            const float* __restrict__ w_out,
                                            ushort_t* __restrict__ w_outT,
                                            float* __restrict__ Oacc,
                                            float* __restrict__ lacc)
{
    int bx = blockIdx.x;
    if (bx < 4096) {
        int i = (bx * 256 + threadIdx.x) * 4;
        float4 v = *(const float4*)&x[i];
        ushort_t o[4] = {f2bf(v.x), f2bf(v.y), f2bf(v.z), f2bf(v.w)};
        *(uint2*)&xb[i] = *(uint2*)o;
    } else if (bx < 4864) {
        int idx = bx - 4096;                     // w_in: [512][1536] -> [1536][512]
        transpose_tile(w_in, w_inT, DH, 3 * DH, idx % 48, idx / 48);
    } else if (bx < 5120) {
        int idx = bx - 4864;                     // w_out: [512][512]
        transpose_tile(w_out, w_outT, DH, DH, idx % 16, idx / 16);
    } else if (bx < 9216) {
        int i = ((bx - 5120) * 256 + threadIdx.x) * 4;   // zero Oacc
        float4 z = {0.f, 0.f, 0.f, 0.f};
        *(float4*)&Oacc[i] = z;
    } else {
        int i = ((bx - 9216) * 256 + threadIdx.x) * 4;   // zero lacc
        float4 z = {0.f, 0.f, 0.f, 0.f};
        *(float4*)&lacc[i] = z;
    }
}

// ---------------------------------------------------------------------------
// bf16 MFMA GEMM (m97 structure, BK=32 -- exact round-0 config). QSCALE:
// multiply cols<512 by C_EXP (folds softmax scale into Q). VTRANS: cols>=1024
// (V) are written ONLY transposed into vtout[b*NH+h][d][l] (8B packed stores).
// Used for the qkv GEMM.
// ---------------------------------------------------------------------------
template <typename OUT, bool QSCALE, bool VTRANS>
__global__ __launch_bounds__(256) void gemm_bt(const ushort_t* __restrict__ A,
                                               const ushort_t* __restrict__ Bt,
                                               const float* __restrict__ bias,
                                               OUT* __restrict__ C,
                                               ushort_t* __restrict__ vtout,
                                               int M, int N, int K)
{
    __shared__ ushort_t As[128 * 32];
    __shared__ ushort_t Bs[128 * 32];
    const int tid = threadIdx.x;
    const int row0 = blockIdx.y * 128, col0 = blockIdx.x * 128;
    const int wid = tid >> 6, lane = tid & 63;
    const int wm = wid >> 1, wn = wid & 1;
    const int quad = lane >> 4, ln = lane & 15;

    f4v acc[4][4] = {};

    const int srow = (lane >> 2);
    const int scol = (lane & 3) * 8;

    for (int k0 = 0; k0 < K; k0 += 32) {
        #pragma unroll
        for (int t = 0; t < 2; t++) {
            int chunk = wid * 2 + t;
            int r = chunk * 16 + srow;
            gld_lds16(&A[(size_t)(row0 + r) * K + k0 + scol], &As[chunk * 512]);
            gld_lds16(&Bt[(size_t)(col0 + r) * K + k0 + scol], &Bs[chunk * 512]);
        }
        __syncthreads();
        s8v af[4], bf[4];
        #pragma unroll
        for (int mt = 0; mt < 4; mt++)
            af[mt] = *(const s8v*)&As[(wm * 64 + mt * 16 + ln) * 32 + quad * 8];
        #pragma unroll
        for (int nt = 0; nt < 4; nt++)
            bf[nt] = *(const s8v*)&Bs[(wn * 64 + nt * 16 + ln) * 32 + quad * 8];
        #pragma unroll
        for (int mt = 0; mt < 4; mt++)
            #pragma unroll
            for (int nt = 0; nt < 4; nt++)
                acc[mt][nt] = __builtin_amdgcn_mfma_f32_16x16x32_bf16(
                    af[mt], bf[nt], acc[mt][nt], 0, 0, 0);
        __syncthreads();
    }

    #pragma unroll
    for (int mt = 0; mt < 4; mt++) {
        #pragma unroll
        for (int nt = 0; nt < 4; nt++) {
            int c = col0 + wn * 64 + nt * 16 + ln;
            float bv = bias[c];
            float scl = 1.0f;
            if constexpr (QSCALE) scl = (c < DH) ? C_EXP : 1.0f;
            bool vcol = false;
            if constexpr (VTRANS) vcol = (c >= 2 * DH);
            if (vcol) {
                // transposed V store: vt[(b*NH+h)*64 + d][l], 4 contiguous l
                int d = c - 2 * DH;
                int hh = d >> 6, dd = d & 63;
                int r0 = row0 + wm * 64 + mt * 16 + quad * 4;
                int bb = r0 >> 12, l = r0 & (LSEQ - 1);
                ushort_t tmp[4];
                #pragma unroll
                for (int reg = 0; reg < 4; reg++)
                    tmp[reg] = f2bf(acc[mt][nt][reg] + bv);
                *(uint2*)&vtout[((size_t)((bb * NH + hh) * 64 + dd)) * LSEQ + l]
                    = *(uint2*)tmp;
            } else {
                #pragma unroll
                for (int reg = 0; reg < 4; reg++) {
                    int r = row0 + wm * 64 + mt * 16 + quad * 4 + reg;
                    float v = (acc[mt][nt][reg] + bv) * scl;
                    if constexpr (sizeof(OUT) == 2)
                        C[(size_t)r * N + c] = (OUT)f2bf(v);
                    else
                        C[(size_t)r * N + c] = v;
                }
            }
        }
    }
}

// ---------------------------------------------------------------------------
// Output GEMM, BN=64 tile (BM=128 x BN=64): grid (512/64=8, 64) = 512 blocks
// = 2 blocks/CU, vs the 128x128 version's 256 blocks = exactly 1/CU (zero
// cross-block latency hiding for a 16-iter 2-barrier loop). 4 waves each own
// a 64x32 sub-tile (acc[4][2]); staging = 8 A-chunks + 4 B-chunks per iter
// (3 gld_lds16/thread); LDS 12KB. Compute loop structure otherwise identical
// to gemm_bt.
// ---------------------------------------------------------------------------
__global__ __launch_bounds__(256) void gemm_out64(const ushort_t* __restrict__ A,
                                                  const ushort_t* __restrict__ Bt,
                                                  const float* __restrict__ bias,
                                                  float* __restrict__ C,
                                                  int M, int N, int K)
{
    __shared__ ushort_t As[128 * 32];   // 8 chunks of 16 rows
    __shared__ ushort_t Bs[64 * 32];    // 4 chunks of 16 rows
    const int tid = threadIdx.x;
    const int row0 = blockIdx.y * 128, col0 = blockIdx.x * 64;
    const int wid = tid >> 6, lane = tid & 63;
    const int wm = wid >> 1, wn = wid & 1;
    const int quad = lane >> 4, ln = lane & 15;

    f4v acc[4][2] = {};

    const int srow = (lane >> 2);
    const int scol = (lane & 3) * 8;

    for (int k0 = 0; k0 < K; k0 += 32) {
        #pragma unroll
        for (int t = 0; t < 2; t++) {
            int ca = wid * 2 + t;                // A chunks 0..7
            int r = ca * 16 + srow;
            gld_lds16(&A[(size_t)(row0 + r) * K + k0 + scol], &As[ca * 512]);
        }
        {
            int cb = wid;                        // B chunks 0..3
            int r = cb * 16 + srow;
            gld_lds16(&Bt[(size_t)(col0 + r) * K + k0 + scol], &Bs[cb * 512]);
        }
        __syncthreads();
        s8v af[4], bf[2];
        #pragma unroll
        for (int mt = 0; mt < 4; mt++)
            af[mt] = *(const s8v*)&As[(wm * 64 + mt * 16 + ln) * 32 + quad * 8];
        #pragma unroll
        for (int nt = 0; nt < 2; nt++)
            bf[nt] = *(const s8v*)&Bs[(wn * 32 + nt * 16 + ln) * 32 + quad * 8];
        #pragma unroll
        for (int mt = 0; mt < 4; mt++)
            #pragma unroll
            for (int nt = 0; nt < 2; nt++)
                acc[mt][nt] = __builtin_amdgcn_mfma_f32_16x16x32_bf16(
                    af[mt], bf[nt], acc[mt][nt], 0, 0, 0);
        __syncthreads();
    }

    #pragma unroll
    for (int mt = 0; mt < 4; mt++) {
        #pragma unroll
        for (int nt = 0; nt < 2; nt++) {
            int c = col0 + wn * 32 + nt * 16 + ln;
            float bv = bias[c];
            #pragma unroll
            for (int reg = 0; reg < 4; reg++) {
                int r = row0 + wm * 64 + mt * 16 + quad * 4 + reg;
                C[(size_t)r * N + c] = acc[mt][nt][reg] + bv;
            }
        }
    }
}

// ---------------------------------------------------------------------------
// Flash v9 (exact round-0 best, ~71us, verified three times). Six structural
// variants (rounds 2-4, 6, 8) all regressed; FROZEN.
// ---------------------------------------------------------------------------
__global__ __launch_bounds__(128) void flash_mfma(const ushort_t* __restrict__ qkv,
                                                  const ushort_t* __restrict__ vt,
                                                  float* __restrict__ Oacc,
                                                  float* __restrict__ lacc)
{
    __shared__ ushort_t Ks[64 * 72];   // [kseq][d]
    __shared__ ushort_t Vs[64 * 72];   // [d][kseq]

    const int p     = blockIdx.x >> 1; // 0..31
    const int khalf = blockIdx.x & 1;
    const int h = blockIdx.y, b = blockIdx.z;
    const int tid = threadIdx.x;
    const int w = tid >> 6, lane = tid & 63;   // w in {0,1}
    const int quad = lane >> 4, ln = lane & 15;

    const int sr = tid >> 1, sc = (tid & 1) * 32;   // staging: 2 threads/row
    const int ldsw = sr * 72 + sc;
    const size_t kstep = (size_t)64 * 3 * DH;

    const int qts[2] = {63 - p, p};

    for (int ti = 0; ti < 2; ti++) {
        const int qt = qts[ti], q0 = qt * 64;
        const int qrow0 = q0 + w * 32;           // this wave's 32 q-rows
        const int n = qt + 1;
        const int ktBeg = khalf ? ((n + 1) >> 1) : 0;
        const int ktEnd = khalf ? n : ((n + 1) >> 1);

        // Q B-frags (pre-scaled by C_EXP), loop-invariant, from global
        s8v qa[2][2];
        #pragma unroll
        for (int qg = 0; qg < 2; qg++) {
            const ushort_t* qrow = qkv
                + ((size_t)(b * LSEQ + qrow0 + qg * 16 + ln)) * (3 * DH) + h * HDIM;
            qa[qg][0] = *(const s8v*)(qrow + quad * 8);
            qa[qg][1] = *(const s8v*)(qrow + 32 + quad * 8);
        }

        float l_s[2] = {0.0f, 0.0f};
        f4v o_acc[2][4] = {};

        if (ktBeg < ktEnd) {
            size_t gk = ((size_t)(b * LSEQ + ktBeg * 64 + sr)) * (3 * DH) + DH + h * HDIM + sc;
            size_t gv = ((size_t)((b * NH + h) * 64 + sr)) * LSEQ + ktBeg * 64 + sc;
            uint4 pk0 = *(const uint4*)&qkv[gk];
            uint4 pk1 = *(const uint4*)&qkv[gk + 8];
            uint4 pk2 = *(const uint4*)&qkv[gk + 16];
            uint4 pk3 = *(const uint4*)&qkv[gk + 24];
            uint4 pv0 = *(const uint4*)&vt[gv];
            uint4 pv1 = *(const uint4*)&vt[gv + 8];
            uint4 pv2 = *(const uint4*)&vt[gv + 16];
            uint4 pv3 = *(const uint4*)&vt[gv + 24];

            for (int kt = ktBeg; kt < ktEnd; kt++) {
                const int k0 = kt * 64;
                __syncthreads();   // all waves done reading prev Ks/Vs
                *(uint4*)&Ks[ldsw]      = pk0;
                *(uint4*)&Ks[ldsw + 8]  = pk1;
                *(uint4*)&Ks[ldsw + 16] = pk2;
                *(uint4*)&Ks[ldsw + 24] = pk3;
                *(uint4*)&Vs[ldsw]      = pv0;
                *(uint4*)&Vs[ldsw + 8]  = pv1;
                *(uint4*)&Vs[ldsw + 16] = pv2;
                *(uint4*)&Vs[ldsw + 24] = pv3;
                if (kt + 1 < ktEnd) {
                    gk += kstep; gv += 64;
                    pk0 = *(const uint4*)&qkv[gk];
                    pk1 = *(const uint4*)&qkv[gk + 8];
                    pk2 = *(const uint4*)&qkv[gk + 16];
                    pk3 = *(const uint4*)&qkv[gk + 24];
                    pv0 = *(const uint4*)&vt[gv];
                    pv1 = *(const uint4*)&vt[gv + 8];
                    pv2 = *(const uint4*)&vt[gv + 16];
                    pv3 = *(const uint4*)&vt[gv + 24];
                }
                __syncthreads();

                // K frags (b128) + V frags (b64 per 16-k chunk), read once
                s8v kb[4][2];
                #pragma unroll
                for (int nt = 0; nt < 4; nt++) {
                    kb[nt][0] = *(const s8v*)&Ks[(nt * 16 + ln) * 72 + quad * 8];
                    kb[nt][1] = *(const s8v*)&Ks[(nt * 16 + ln) * 72 + 32 + quad * 8];
                }
                s4v vf[4][4];   // [dt][chunk]
                #pragma unroll
                for (int dt = 0; dt < 4; dt++)
                    #pragma unroll
                    for (int nt = 0; nt < 4; nt++)
                        vf[dt][nt] = *(const s4v*)&Vs[(dt * 16 + ln) * 72 + nt * 16 + quad * 4];

                #pragma unroll
                for (int qg = 0; qg < 2; qg++) {
                    // S^T[k0+nt*16+quad*4+reg][qrow0+qg*16+ln]
                    f4v s[4] = {};
                    #pragma unroll
                    for (int nt = 0; nt < 4; nt++) {
                        s[nt] = __builtin_amdgcn_mfma_f32_16x16x32_bf16(kb[nt][0], qa[qg][0], s[nt], 0, 0, 0);
                        s[nt] = __builtin_amdgcn_mfma_f32_16x16x32_bf16(kb[nt][1], qa[qg][1], s[nt], 0, 0, 0);
                    }

                    float pp[4][4];
                    const int q = qrow0 + qg * 16 + ln;
                    if (kt == qt) {
                        #pragma unroll
                        for (int nt = 0; nt < 4; nt++) {
                            #pragma unroll
                            for (int reg = 0; reg < 4; reg++) {
                                int kidx = k0 + nt * 16 + quad * 4 + reg;
                                bool valid = (kidx <= q) && (kidx >= 1 || q == 0);
                                pp[nt][reg] = valid ? __builtin_amdgcn_exp2f(s[nt][reg]) : 0.0f;
                            }
                        }
                    } else {
                        #pragma unroll
                        for (int nt = 0; nt < 4; nt++)
                            #pragma unroll
                            for (int reg = 0; reg < 4; reg++)
                                pp[nt][reg] = __builtin_amdgcn_exp2f(s[nt][reg]);
                        if (kt == 0 && quad == 0)   // k==0 invalid (q >= 64 here)
                            pp[0][0] = 0.0f;
                    }

                    #pragma unroll
                    for (int nt = 0; nt < 4; nt++)
                        l_s[qg] += (pp[nt][0] + pp[nt][1]) + (pp[nt][2] + pp[nt][3]);

                    // P stays in registers: truncation-packed bf16 A-operand
                    #pragma unroll
                    for (int nt = 0; nt < 4; nt++) {
                        union { unsigned int u[2]; s4v v; } pk;
                        pk.u[0] = pk_trunc(pp[nt][0], pp[nt][1]);
                        pk.u[1] = pk_trunc(pp[nt][2], pp[nt][3]);
                        #pragma unroll
                        for (int dt = 0; dt < 4; dt++)
                            o_acc[qg][dt] = __builtin_amdgcn_mfma_f32_16x16x16bf16_1k(
                                pk.v, vf[dt][nt], o_acc[qg][dt], 0, 0, 0);
                    }
                }
            }
        }

        // merge partials (device-scope atomics; 2 writers per address)
        #pragma unroll
        for (int qg = 0; qg < 2; qg++) {
            float lf = l_s[qg];
            lf += __shfl_xor(lf, 16);
            lf += __shfl_xor(lf, 32);
            if (quad == 0)
                atomicAdd(&lacc[((size_t)(b * NH + h)) * LSEQ + qrow0 + qg * 16 + ln], lf);
            #pragma unroll
            for (int dt = 0; dt < 4; dt++)
                #pragma unroll
                for (int reg = 0; reg < 4; reg++)
                    atomicAdd(&Oacc[((size_t)(b * LSEQ + qrow0 + qg * 16 + quad * 4 + reg)) * DH
                                    + h * HDIM + dt * 16 + ln],
                              o_acc[qg][dt][reg]);
        }
    }
}

// ---------------------------------------------------------------------------
// att[b,l,h*64+d] = Oacc / lacc  (fp32 -> bf16). 16 elems/thread.
// (exact round-0 version)
// ---------------------------------------------------------------------------
__global__ __launch_bounds__(256) void normalize(const float* __restrict__ Oacc,
                                                 const float* __restrict__ lacc,
                                                 ushort_t* __restrict__ att)
{
    int t = blockIdx.x * 256 + threadIdx.x;   // 262144 threads
    int row = t >> 5;                          // 0..8191
    int col0 = (t & 31) * 16;
    int h = col0 >> 6;
    int b = row >> 12, l = row & (LSEQ - 1);
    float linv = 1.0f / lacc[((size_t)(b * NH + h)) * LSEQ + l];
    const float* o = &Oacc[(size_t)row * DH + col0];
    ushort_t tmp[16];
    #pragma unroll
    for (int j = 0; j < 16; j++) tmp[j] = f2bf(o[j] * linv);
    size_t g = (size_t)row * DH + col0;
    *(uint4*)&att[g]     = *(uint4*)&tmp[0];
    *(uint4*)&att[g + 8] = *(uint4*)&tmp[8];
}

// ---------------------------------------------------------------------------
extern "C" void kernel_launch(void* const* d_in, const int* in_sizes, int n_in,
                              void* d_out, int out_size, void* d_ws, size_t ws_size,
                              hipStream_t stream)
{
    const float* x     = (const float*)d_in[0];  // [2,4096,512]
    const float* w_in  = (const float*)d_in[1];  // [512,1536]
    const float* b_in  = (const float*)d_in[2];  // [1536]
    const float* w_out = (const float*)d_in[3];  // [512,512]
    const float* b_out = (const float*)d_in[4];  // [512]
    float* out = (float*)d_out;                  // [2,4096,512] fp32

    const int M = BSZ * LSEQ;                    // 8192
    char* ws = (char*)d_ws;
    ushort_t* xb    = (ushort_t*)ws;                       ws += (size_t)M * DH * 2;        // 8.4MB
    ushort_t* w_inT = (ushort_t*)ws;                       ws += (size_t)3 * DH * DH * 2;   // 1.6MB
    ushort_t* w_outT= (ushort_t*)ws;                       ws += (size_t)DH * DH * 2;       // 0.5MB
    ushort_t* qkvb  = (ushort_t*)ws;                       ws += (size_t)M * 3 * DH * 2;    // 25.2MB
    ushort_t* vtb   = (ushort_t*)ws;                       ws += (size_t)M * DH * 2;        // 8.4MB
    ushort_t* attb  = (ushort_t*)ws;                       ws += (size_t)M * DH * 2;        // 8.4MB
    float*    Oacc  = (float*)ws;                          ws += (size_t)M * DH * 4;        // 16.8MB
    float*    lacc  = (float*)ws;                          /* 256KB */

    prep<<<9280, 256, 0, stream>>>(x, xb, w_in, w_inT, w_out, w_outT, Oacc, lacc);

    // qkv GEMM: scales Q cols by C_EXP, writes V cols transposed into vtb
    gemm_bt<ushort_t, true, true><<<dim3(3 * DH / 128, M / 128), 256, 0, stream>>>(
        xb, w_inT, b_in, qkvb, vtb, M, 3 * DH, DH);

    flash_mfma<<<dim3(64, NH, BSZ), 128, 0, stream>>>(qkvb, vtb, Oacc, lacc);

    normalize<<<1024, 256, 0, stream>>>(Oacc, lacc, attb);

    // output GEMM: BN=64 tile -> 512 blocks = 2 blocks/CU (was 256 = 1/CU)
    gemm_out64<<<dim3(DH / 64, M / 128), 256, 0, stream>>>(
        attb, w_outT, b_out, out, M, DH, DH);
}